// Round 5
// baseline (619.945 us; speedup 1.0000x reference)
//
// Round 5: (1) XOR k-slot LDS swizzle in all MFMA GEMMs (8-way -> 4-way bank
// conflicts), (2) launch fusion: one prep kernel (6 transposes + bias concat +
// cnt zero), one fused qkvg launch for img+txt, (3) FFN2 split-K accumulates
// via fp32 atomicAdd into d_out after route_pre seeds bias/copies.
#include <hip/hip_runtime.h>
#include <hip/hip_bf16.h>
#include <math.h>

#define NB 16384      // B
#define DIM 1024      // D
#define CAP 6656      // compacted capacity (52 m-tiles; count ~5461)
#define MT 52         // CAP/128 m-tiles

using bf16 = __hip_bfloat16;
typedef __attribute__((ext_vector_type(8))) short short8;
typedef __attribute__((ext_vector_type(4))) short short4v;
typedef __attribute__((ext_vector_type(4))) float float4v;

__device__ __forceinline__ void gl_lds16(const void* g, void* l) {
  __builtin_amdgcn_global_load_lds(
      (const __attribute__((address_space(1))) unsigned int*)g,
      (__attribute__((address_space(3))) unsigned int*)l, 16, 0, 0);
}

__device__ __forceinline__ short f2bf(float x) {
  __hip_bfloat16 h = __float2bfloat16(x);
  return *reinterpret_cast<short*>(&h);
}

// bid -> (m0, n0): xcd = bid&7 owns n-panels n%8==xcd; m slow.
__device__ __forceinline__ void swz(int bid, int nN, int& m0, int& n0) {
  int x = bid & 7;
  int r = bid >> 3;
  int nl = nN >> 3;
  int nLoc = r % nl;
  int m = r / nl;
  n0 = (x + 8 * nLoc) * 128;
  m0 = m * 128;
}

// Staged load of one 128x32 tile with XOR k-slot swizzle.
// LDS linear pos (row,slot): row*64B + slot*16B holds global k-part slot^(row&3).
#define STAGE_TILE(SRC, LD, DST)                                              \
  {                                                                           \
    int row = c >> 2, sslot = c & 3;                                          \
    int kp = sslot ^ (row & 3);                                               \
    gl_lds16((SRC) + (size_t)row * (LD) + k0 + kp * 8,                        \
             (void*)((DST) + j * 2048 + wave * 512));                         \
  }

// ---------------- fused prep: 6 transposes + bias concat + cnt zero --------
// transpose blocks: 32x8 threads, 32x32 tile; (K,N) fp32 -> (N,K) bf16
__device__ __forceinline__ void tr_tile(const float* in, bf16* out, int K, int N,
                                        int tile) {
  __shared__ float tl[32][33];
  int nx = N / 32;
  int n0 = (tile % nx) * 32, k0 = (tile / nx) * 32;
  int tx = threadIdx.x, ty = threadIdx.y;
#pragma unroll
  for (int i = 0; i < 32; i += 8)
    tl[ty + i][tx] = in[(size_t)(k0 + ty + i) * N + n0 + tx];
  __syncthreads();
#pragma unroll
  for (int i = 0; i < 32; i += 8)
    out[(size_t)(n0 + ty + i) * K + k0 + tx] = __float2bfloat16(tl[tx][ty + i]);
}

__global__ __launch_bounds__(256) void prep_kernel(
    const float* __restrict__ Wqkv, const float* __restrict__ Wg,
    const float* __restrict__ Wo, const float* __restrict__ Wf1,
    const float* __restrict__ Wf2, const float* __restrict__ bqkv,
    const float* __restrict__ bg, bf16* __restrict__ WqkvT,
    bf16* __restrict__ WgTopT, bf16* __restrict__ WgBotT, bf16* __restrict__ WoT,
    bf16* __restrict__ Wf1T, bf16* __restrict__ Wf2T, float* __restrict__ biasA,
    float* __restrict__ biasB, int* __restrict__ cnt) {
  int bid = blockIdx.x;
  if (bid == 0 && threadIdx.x == 0 && threadIdx.y == 0) *cnt = 0;
  if (bid < 3072) { tr_tile(Wqkv, WqkvT, 1024, 3072, bid); return; }
  bid -= 3072;
  if (bid < 1024) { tr_tile(Wg, WgTopT, 1024, 1024, bid); return; }
  bid -= 1024;
  if (bid < 1024) { tr_tile(Wg + 1024 * 1024, WgBotT, 1024, 1024, bid); return; }
  bid -= 1024;
  if (bid < 1024) { tr_tile(Wo, WoT, 1024, 1024, bid); return; }
  bid -= 1024;
  if (bid < 4096) { tr_tile(Wf1, Wf1T, 1024, 4096, bid); return; }
  bid -= 4096;
  if (bid < 4096) { tr_tile(Wf2, Wf2T, 4096, 1024, bid); return; }
  bid -= 4096;
  // bias blocks: 16 blocks x 256 threads = 4096
  int i = bid * 256 + threadIdx.y * 32 + threadIdx.x;
  float qv = (i < 3072) ? bqkv[i] : 0.f;
  biasA[i] = qv;
  biasB[i] = (i < 3072) ? qv : bg[i - 3072];
}

// ---------------- compaction ----------------
__global__ __launch_bounds__(256) void index_build(const int* __restrict__ route,
                                                   int* __restrict__ cnt,
                                                   int* __restrict__ idx) {
  int r = blockIdx.x * 256 + threadIdx.x;
  if (r < NB && route[r] == 2) {
    int p = atomicAdd(cnt, 1);
    idx[p] = r;
  }
}

__global__ __launch_bounds__(256) void gather_cast(
    const float* __restrict__ img, const float* __restrict__ txt,
    const int* __restrict__ cnt, const int* __restrict__ idx,
    bf16* __restrict__ xg, bf16* __restrict__ tg) {
  int n = blockIdx.x;
  if (n >= *cnt) return;
  int r = idx[n];
  int c = threadIdx.x * 4;
  float4 vi = *(const float4*)(img + (size_t)r * DIM + c);
  float4 vt = *(const float4*)(txt + (size_t)r * DIM + c);
  short4v pi, pt;
  pi[0] = f2bf(vi.x); pi[1] = f2bf(vi.y); pi[2] = f2bf(vi.z); pi[3] = f2bf(vi.w);
  pt[0] = f2bf(vt.x); pt[1] = f2bf(vt.y); pt[2] = f2bf(vt.z); pt[3] = f2bf(vt.w);
  *(short4v*)(xg + (size_t)n * DIM + c) = pi;
  *(short4v*)(tg + (size_t)n * DIM + c) = pt;
}

// ---------------- qkv+gate GEMM, fused img/txt via blockIdx.y --------------
// out bf16 [CAP][4096]: cols 0-3071 qkv, 3072-4095 gate partial (pre-sigmoid)
__global__ __launch_bounds__(256) void gemm_qkvg(
    const bf16* __restrict__ xg, const bf16* __restrict__ tg,
    const bf16* __restrict__ BtQ, const bf16* __restrict__ BtGT,
    const bf16* __restrict__ BtGB, const float* __restrict__ biasA,
    const float* __restrict__ biasB, bf16* __restrict__ qx,
    bf16* __restrict__ tx, const int* __restrict__ cntp) {
  const int cnt = *cntp;
  int m0, n0;
  swz(blockIdx.x, 32, m0, n0);
  if (m0 >= ((cnt + 127) & ~127)) return;
  const int src = blockIdx.y;
  const bf16* A0 = src ? tg : xg;
  const bf16* BtG = src ? BtGB : BtGT;
  const float* bias = src ? biasB : biasA;
  bf16* outp = src ? tx : qx;
  alignas(16) __shared__ bf16 sA[128 * 32];
  alignas(16) __shared__ bf16 sB[128 * 32];
  const int t = threadIdx.x;
  const int wave = t >> 6, lane = t & 63;
  const int wm = (wave >> 1) * 64, wn = (wave & 1) * 64;
  const int r16 = lane & 15, quad = lane >> 4;
  const int sl = (quad ^ (r16 & 3)) * 8;  // XOR k-slot (bank de-conflict)
  const bf16* Bt = (n0 < 3072) ? BtQ + (size_t)n0 * 1024 : BtG + (size_t)(n0 - 3072) * 1024;

  float4v acc[4][4] = {};
  for (int k0 = 0; k0 < 1024; k0 += 32) {
    if (k0) __syncthreads();
#pragma unroll
    for (int j = 0; j < 2; ++j) {
      int c = t + j * 256;
      STAGE_TILE(Bt, 1024, sB)
      STAGE_TILE(A0 + (size_t)m0 * 1024, 1024, sA)
    }
    __syncthreads();
    short8 af[4], bfr[4];
#pragma unroll
    for (int i = 0; i < 4; ++i) {
      af[i] = *(const short8*)(sA + (wm + i * 16 + r16) * 32 + sl);
      bfr[i] = *(const short8*)(sB + (wn + i * 16 + r16) * 32 + sl);
    }
#pragma unroll
    for (int i = 0; i < 4; ++i)
#pragma unroll
      for (int j = 0; j < 4; ++j)
        acc[i][j] =
            __builtin_amdgcn_mfma_f32_16x16x32_bf16(af[i], bfr[j], acc[i][j], 0, 0, 0);
  }
#pragma unroll
  for (int i = 0; i < 4; ++i)
#pragma unroll
    for (int j = 0; j < 4; ++j) {
      int gcol = n0 + wn + j * 16 + r16;
      float bv = bias[gcol];
#pragma unroll
      for (int r = 0; r < 4; ++r) {
        int grow = m0 + wm + i * 16 + (lane >> 4) * 4 + r;
        outp[(size_t)grow * 4096 + gcol] = __float2bfloat16(acc[i][j][r] + bv);
      }
    }
}

// ---------------- seq-len-2 attention ----------------
__global__ __launch_bounds__(256) void attn_kernel(const bf16* __restrict__ qx,
                                                   const bf16* __restrict__ tx,
                                                   bf16* __restrict__ cmean,
                                                   const int* __restrict__ cntp) {
  const int cnt = *cntp;
  int gw = blockIdx.x * 4 + (threadIdx.x >> 6);
  int lane = threadIdx.x & 63;
  int n = gw >> 4, h = gw & 15;
  if (n >= ((cnt + 127) & ~127)) return;
  const bf16* b0 = qx + (size_t)n * 4096 + h * 64 + lane;
  const bf16* b1 = tx + (size_t)n * 4096 + h * 64 + lane;
  float q0 = __bfloat162float(b0[0]);
  float k0 = __bfloat162float(b0[1024]);
  float v0 = __bfloat162float(b0[2048]);
  float q1 = __bfloat162float(b1[0]);
  float k1 = __bfloat162float(b1[1024]);
  float v1 = __bfloat162float(b1[2048]);
  float s00 = q0 * k0, s01 = q0 * k1, s10 = q1 * k0, s11 = q1 * k1;
#pragma unroll
  for (int d = 32; d > 0; d >>= 1) {
    s00 += __shfl_xor(s00, d);
    s01 += __shfl_xor(s01, d);
    s10 += __shfl_xor(s10, d);
    s11 += __shfl_xor(s11, d);
  }
  const float sc = 0.125f;
  s00 *= sc; s01 *= sc; s10 *= sc; s11 *= sc;
  float m0 = fmaxf(s00, s01), m1 = fmaxf(s10, s11);
  float e00 = expf(s00 - m0), e01 = expf(s01 - m0);
  float e10 = expf(s10 - m1), e11 = expf(s11 - m1);
  float i0 = 1.f / (e00 + e01), i1 = 1.f / (e10 + e11);
  float c0 = (e00 * i0) * v0 + (e01 * i0) * v1;
  float c1 = (e10 * i1) * v0 + (e11 * i1) * v1;
  cmean[(size_t)n * DIM + h * 64 + lane] = __float2bfloat16(0.5f * (c0 + c1));
}

// ---------------- wo_z: z = sigmoid-gate mix + cmean@Wo + bo ----------------
__global__ __launch_bounds__(256) void wo_z_kernel(
    const float* __restrict__ img, const float* __restrict__ txt,
    const bf16* __restrict__ qx, const bf16* __restrict__ tx,
    const bf16* __restrict__ WoT, const float* __restrict__ bg,
    const float* __restrict__ bo, const bf16* __restrict__ cmean,
    bf16* __restrict__ z, const int* __restrict__ cntp, const int* __restrict__ idx) {
  const int cnt = *cntp;
  int m0, n0;
  swz(blockIdx.x, 8, m0, n0);
  if (m0 >= ((cnt + 127) & ~127)) return;
  alignas(16) __shared__ bf16 sA[128 * 32];
  alignas(16) __shared__ bf16 sB[128 * 32];
  const int t = threadIdx.x;
  const int wave = t >> 6, lane = t & 63;
  const int wm = (wave >> 1) * 64, wn = (wave & 1) * 64;
  const int r16 = lane & 15, quad = lane >> 4;
  const int sl = (quad ^ (r16 & 3)) * 8;

  float4v acc[4][4] = {};
  for (int k0 = 0; k0 < 1024; k0 += 32) {
    if (k0) __syncthreads();
#pragma unroll
    for (int j = 0; j < 2; ++j) {
      int c = t + j * 256;
      STAGE_TILE(WoT + (size_t)n0 * 1024, 1024, sB)
      STAGE_TILE(cmean + (size_t)m0 * 1024, 1024, sA)
    }
    __syncthreads();
    short8 af[4], bfr[4];
#pragma unroll
    for (int i = 0; i < 4; ++i) {
      af[i] = *(const short8*)(sA + (wm + i * 16 + r16) * 32 + sl);
      bfr[i] = *(const short8*)(sB + (wn + i * 16 + r16) * 32 + sl);
    }
#pragma unroll
    for (int i = 0; i < 4; ++i)
#pragma unroll
      for (int j = 0; j < 4; ++j)
        acc[i][j] =
            __builtin_amdgcn_mfma_f32_16x16x32_bf16(af[i], bfr[j], acc[i][j], 0, 0, 0);
  }
#pragma unroll
  for (int i = 0; i < 4; ++i)
#pragma unroll
    for (int j = 0; j < 4; ++j) {
      int gcol = n0 + wn + j * 16 + r16;
      float bgv = bg[gcol], bov = bo[gcol];
#pragma unroll
      for (int r = 0; r < 4; ++r) {
        int grow = m0 + wm + i * 16 + quad * 4 + r;
        float zv = 0.f;
        if (grow < cnt) {
          int orow = idx[grow];
          float gp = __bfloat162float(qx[(size_t)grow * 4096 + 3072 + gcol]) +
                     __bfloat162float(tx[(size_t)grow * 4096 + 3072 + gcol]) + bgv;
          float g = 1.f / (1.f + expf(-gp));
          size_t ii = (size_t)orow * DIM + gcol;
          float fm = g * img[ii] + (1.f - g) * txt[ii];
          zv = fm + acc[i][j][r] + bov;
        }
        z[(size_t)grow * DIM + gcol] = __float2bfloat16(zv);
      }
    }
}

// ---------------- layernorm in-place ----------------
__global__ __launch_bounds__(256) void ln_kernel(bf16* __restrict__ z,
                                                 const float* __restrict__ g,
                                                 const float* __restrict__ be,
                                                 const int* __restrict__ cntp) {
  const int cnt = *cntp;
  int b = blockIdx.x, t = threadIdx.x;
  if (b >= ((cnt + 127) & ~127)) return;
  bf16* zr = z + (size_t)b * DIM;
  float v[4];
  float s = 0.f, s2 = 0.f;
#pragma unroll
  for (int i = 0; i < 4; ++i) {
    float x = __bfloat162float(zr[t + 256 * i]);
    v[i] = x; s += x; s2 += x * x;
  }
#pragma unroll
  for (int d = 32; d > 0; d >>= 1) {
    s += __shfl_xor(s, d);
    s2 += __shfl_xor(s2, d);
  }
  __shared__ float rs[4], rs2[4];
  int w = t >> 6, lane = t & 63;
  if (!lane) { rs[w] = s; rs2[w] = s2; }
  __syncthreads();
  s = rs[0] + rs[1] + rs[2] + rs[3];
  s2 = rs2[0] + rs2[1] + rs2[2] + rs2[3];
  float mu = s * (1.f / 1024.f);
  float var = s2 * (1.f / 1024.f) - mu * mu;
  float r = rsqrtf(var + 1e-5f);
#pragma unroll
  for (int i = 0; i < 4; ++i) {
    int c = t + 256 * i;
    zr[c] = __float2bfloat16((v[i] - mu) * r * g[c] + be[c]);
  }
}

// ---------------- ffn1: h = gelu(z@Wf1 + bf1), N=4096, K=1024 --------------
__global__ __launch_bounds__(256) void gemm_gelu(
    const bf16* __restrict__ A0, const bf16* __restrict__ Bt,
    const float* __restrict__ bias, bf16* __restrict__ outp,
    const int* __restrict__ cntp) {
  const int cnt = *cntp;
  int m0, n0;
  swz(blockIdx.x, 32, m0, n0);
  if (m0 >= ((cnt + 127) & ~127)) return;
  alignas(16) __shared__ bf16 sA[128 * 32];
  alignas(16) __shared__ bf16 sB[128 * 32];
  const int t = threadIdx.x;
  const int wave = t >> 6, lane = t & 63;
  const int wm = (wave >> 1) * 64, wn = (wave & 1) * 64;
  const int r16 = lane & 15, quad = lane >> 4;
  const int sl = (quad ^ (r16 & 3)) * 8;

  float4v acc[4][4] = {};
  for (int k0 = 0; k0 < 1024; k0 += 32) {
    if (k0) __syncthreads();
#pragma unroll
    for (int j = 0; j < 2; ++j) {
      int c = t + j * 256;
      STAGE_TILE(Bt + (size_t)n0 * 1024, 1024, sB)
      STAGE_TILE(A0 + (size_t)m0 * 1024, 1024, sA)
    }
    __syncthreads();
    short8 af[4], bfr[4];
#pragma unroll
    for (int i = 0; i < 4; ++i) {
      af[i] = *(const short8*)(sA + (wm + i * 16 + r16) * 32 + sl);
      bfr[i] = *(const short8*)(sB + (wn + i * 16 + r16) * 32 + sl);
    }
#pragma unroll
    for (int i = 0; i < 4; ++i)
#pragma unroll
      for (int j = 0; j < 4; ++j)
        acc[i][j] =
            __builtin_amdgcn_mfma_f32_16x16x32_bf16(af[i], bfr[j], acc[i][j], 0, 0, 0);
  }
#pragma unroll
  for (int i = 0; i < 4; ++i)
#pragma unroll
    for (int j = 0; j < 4; ++j) {
      int gcol = n0 + wn + j * 16 + r16;
      float bv = bias[gcol];
#pragma unroll
      for (int r = 0; r < 4; ++r) {
        int grow = m0 + wm + i * 16 + quad * 4 + r;
        float v = acc[i][j][r] + bv;
        float gl = 0.5f * v * (1.f + erff(v * 0.70710678118654752f));
        outp[(size_t)grow * 4096 + gcol] = __float2bfloat16(gl);
      }
    }
}

// ---------------- route_pre: seed d_out (copies + bf2 bias for rc2) --------
__global__ __launch_bounds__(256) void route_pre(
    const float* __restrict__ img, const float* __restrict__ txt,
    const int* __restrict__ route, const float* __restrict__ bf2,
    float* __restrict__ out) {
  int row = blockIdx.x;
  int rc = route[row];
  int c = threadIdx.x * 4;
  float4 v;
  if (rc == 2) {
    v = *(const float4*)(bf2 + c);
  } else {
    const float* src = (rc == 0) ? img : txt;
    v = *(const float4*)(src + (size_t)row * DIM + c);
  }
  *(float4*)(out + (size_t)row * DIM + c) = v;
}

// ---------------- ffn2 split-K: atomicAdd slices into d_out ----------------
__global__ __launch_bounds__(256) void gemm_splitk(
    const bf16* __restrict__ A0, const bf16* __restrict__ Bt,
    float* __restrict__ out, const int* __restrict__ cntp,
    const int* __restrict__ idx) {
  const int cnt = *cntp;
  int m0, n0;
  swz(blockIdx.x, 8, m0, n0);
  if (m0 >= ((cnt + 127) & ~127)) return;
  const int kbase = blockIdx.y * 2048;
  alignas(16) __shared__ bf16 sA[128 * 32];
  alignas(16) __shared__ bf16 sB[128 * 32];
  const int t = threadIdx.x;
  const int wave = t >> 6, lane = t & 63;
  const int wm = (wave >> 1) * 64, wn = (wave & 1) * 64;
  const int r16 = lane & 15, quad = lane >> 4;
  const int sl = (quad ^ (r16 & 3)) * 8;

  float4v acc[4][4] = {};
  for (int k0 = kbase; k0 < kbase + 2048; k0 += 32) {
    if (k0 != kbase) __syncthreads();
#pragma unroll
    for (int j = 0; j < 2; ++j) {
      int c = t + j * 256;
      STAGE_TILE(Bt + (size_t)n0 * 4096, 4096, sB)
      STAGE_TILE(A0 + (size_t)m0 * 4096, 4096, sA)
    }
    __syncthreads();
    short8 af[4], bfr[4];
#pragma unroll
    for (int i = 0; i < 4; ++i) {
      af[i] = *(const short8*)(sA + (wm + i * 16 + r16) * 32 + sl);
      bfr[i] = *(const short8*)(sB + (wn + i * 16 + r16) * 32 + sl);
    }
#pragma unroll
    for (int i = 0; i < 4; ++i)
#pragma unroll
      for (int j = 0; j < 4; ++j)
        acc[i][j] =
            __builtin_amdgcn_mfma_f32_16x16x32_bf16(af[i], bfr[j], acc[i][j], 0, 0, 0);
  }
#pragma unroll
  for (int i = 0; i < 4; ++i)
#pragma unroll
    for (int j = 0; j < 4; ++j) {
      int gcol = n0 + wn + j * 16 + r16;
#pragma unroll
      for (int r = 0; r < 4; ++r) {
        int grow = m0 + wm + i * 16 + quad * 4 + r;
        if (grow < cnt) {
          int orow = idx[grow];
          atomicAdd(out + (size_t)orow * DIM + gcol, acc[i][j][r]);
        }
      }
    }
}

extern "C" void kernel_launch(void* const* d_in, const int* in_sizes, int n_in,
                              void* d_out, int out_size, void* d_ws, size_t ws_size,
                              hipStream_t stream) {
  const float* img = (const float*)d_in[0];
  const float* txt = (const float*)d_in[1];
  const int* route = (const int*)d_in[2];
  const float* Wg = (const float*)d_in[3];
  const float* bg = (const float*)d_in[4];
  const float* Wqkv = (const float*)d_in[5];
  const float* bqkv = (const float*)d_in[6];
  const float* Wo = (const float*)d_in[7];
  const float* bo = (const float*)d_in[8];
  const float* gamma = (const float*)d_in[9];
  const float* beta = (const float*)d_in[10];
  const float* Wf1 = (const float*)d_in[11];
  const float* bf1 = (const float*)d_in[12];
  const float* Wf2 = (const float*)d_in[13];
  const float* bf2 = (const float*)d_in[14];

  char* ws = (char*)d_ws;
  size_t off = 0;
  auto alloc = [&](size_t bytes) {
    char* p = ws + off;
    off += (bytes + 255) & ~(size_t)255;
    return p;
  };
  int* cntp = (int*)alloc(256);
  int* idx = (int*)alloc((size_t)NB * 4);
  float* biasA = (float*)alloc(4096 * 4);
  float* biasB = (float*)alloc(4096 * 4);
  bf16* WqkvT = (bf16*)alloc((size_t)3072 * 1024 * 2);
  bf16* WgTopT = (bf16*)alloc((size_t)1024 * 1024 * 2);
  bf16* WgBotT = (bf16*)alloc((size_t)1024 * 1024 * 2);
  bf16* WoT = (bf16*)alloc((size_t)1024 * 1024 * 2);
  bf16* Wf1T = (bf16*)alloc((size_t)4096 * 1024 * 2);
  bf16* Wf2T = (bf16*)alloc((size_t)1024 * 4096 * 2);
  bf16* xg = (bf16*)alloc((size_t)CAP * 1024 * 2);
  bf16* tg = (bf16*)alloc((size_t)CAP * 1024 * 2);
  bf16* qx = (bf16*)alloc((size_t)CAP * 4096 * 2);  // qkv+gate (img); later h
  bf16* tx = (bf16*)alloc((size_t)CAP * 4096 * 2);  // qkv+gate (txt)
  bf16* cmean = (bf16*)alloc((size_t)CAP * 1024 * 2);
  bf16* zb = (bf16*)alloc((size_t)CAP * 1024 * 2);
  bf16* hb = qx;  // h (CAP x 4096) reuses qx after attn+wo_z consumed it

  // prep: 3072+1024*3+4096*2+16 = 14352 blocks
  prep_kernel<<<14352, dim3(32, 8), 0, stream>>>(
      Wqkv, Wg, Wo, Wf1, Wf2, bqkv, bg, WqkvT, WgTopT, WgBotT, WoT, Wf1T, Wf2T,
      biasA, biasB, cntp);
  index_build<<<NB / 256, 256, 0, stream>>>(route, cntp, idx);
  gather_cast<<<CAP, 256, 0, stream>>>(img, txt, cntp, idx, xg, tg);

  // qkv+gate, both positions in one launch
  gemm_qkvg<<<dim3(32 * MT, 2), 256, 0, stream>>>(xg, tg, WqkvT, WgTopT, WgBotT,
                                                  biasA, biasB, qx, tx, cntp);
  attn_kernel<<<CAP * 4, 256, 0, stream>>>(qx, tx, cmean, cntp);
  wo_z_kernel<<<8 * MT, 256, 0, stream>>>(img, txt, qx, tx, WoT, bg, bo, cmean, zb,
                                          cntp, idx);
  ln_kernel<<<CAP, 256, 0, stream>>>(zb, gamma, beta, cntp);
  gemm_gelu<<<32 * MT, 256, 0, stream>>>(zb, Wf1T, bf1, hb, cntp);
  // seed outputs (rc0/1 copies; bf2 bias into rc2 rows), then atomic split-K
  route_pre<<<NB, 256, 0, stream>>>(img, txt, route, bf2, (float*)d_out);
  gemm_splitk<<<dim3(8 * MT, 2), 256, 0, stream>>>(hb, Wf2T, (float*)d_out, cntp, idx);
}